// Round 12
// baseline (191.608 us; speedup 1.0000x reference)
//
#include <hip/hip_runtime.h>
#include <hip/hip_bf16.h>

#define HW 1024
#define C_CH 768
#define BATCH 16
#define NG 32
#define CPG 24
#define EPS 1e-5f

typedef __attribute__((ext_vector_type(8))) short bf16x8;
typedef __attribute__((ext_vector_type(4))) float f32x4;
typedef unsigned short u16;
typedef unsigned int u32;

typedef const __attribute__((address_space(1))) void* gas_ptr;
typedef __attribute__((address_space(3))) void* las_ptr;

__device__ __forceinline__ void load_lds16(const void* g, void* l) {
    __builtin_amdgcn_global_load_lds((gas_ptr)g, (las_ptr)l, 16, 0, 0);
}

__device__ __forceinline__ u16 f2bf(float f) {
    __hip_bfloat16 h = __float2bfloat16(f);
    return *(u16*)&h;
}
__device__ __forceinline__ float bf2f(u16 u) {
    return __uint_as_float(((u32)u) << 16);
}

// Bijective XCD-chunked swizzle (R6-verified win).
__device__ __forceinline__ void xcd_remap(int& bx, int& by, int& bz) {
    const int nbx = gridDim.x, nby = gridDim.y;
    const int nwg = nbx * nby * gridDim.z;
    int bid = blockIdx.x + nbx * (blockIdx.y + nby * blockIdx.z);
    if ((nwg & 7) == 0) {
        const int q = nwg >> 3;
        bid = (bid & 7) * q + (bid >> 3);
    }
    bx = bid % nbx;
    int t2 = bid / nbx;
    by = t2 % nby;
    bz = t2 / nby;
}

// ---------------- merged weight cast f32 -> bf16 (both arrays, ONE launch) ----------------
#define N4_QKV ((3 * C_CH * C_CH) / 4)
#define N4_OUT ((C_CH * C_CH) / 4)
__global__ __launch_bounds__(256) void cast_weights_kernel(const float4* __restrict__ wqkv,
                                                           const float4* __restrict__ wout,
                                                           ushort4* __restrict__ outQ,
                                                           ushort4* __restrict__ outO) {
    int i = blockIdx.x * 256 + threadIdx.x;
    const float4* src;
    ushort4* dst;
    int idx;
    if (i < N4_QKV) { src = wqkv; dst = outQ; idx = i; }
    else if (i < N4_QKV + N4_OUT) { src = wout; dst = outO; idx = i - N4_QKV; }
    else return;
    float4 v = src[idx];
    ushort4 u;
    u.x = f2bf(v.x); u.y = f2bf(v.y); u.z = f2bf(v.z); u.w = f2bf(v.w);
    dst[idx] = u;
}

// ---------- Fused GroupNorm: stats + normalize + transpose in ONE pass (R9-verified) ----------
__global__ __launch_bounds__(512) void gn_fused_kernel(const float* __restrict__ x,
                                                       const float* __restrict__ gamma,
                                                       const float* __restrict__ beta,
                                                       __hip_bfloat16* __restrict__ xnT) {
    __shared__ float lds[24 * 1025];
    __shared__ float red[18];
    __shared__ float lga[24], lbe[24];
    const int bg = blockIdx.x;
    const int b = bg >> 5, g = bg & 31;
    const int t = threadIdx.x;
    const float4* src = (const float4*)(x + (size_t)bg * (CPG * HW));

    float s = 0.f, s2 = 0.f;
#pragma unroll 4
    for (int i = 0; i < 12; i++) {
        int fl4 = i * 512 + t;
        float4 v = src[fl4];
        int flat = fl4 * 4;
        int c = flat >> 10, p = flat & 1023;
        float* d = &lds[c * 1025 + p];
        d[0] = v.x; d[1] = v.y; d[2] = v.z; d[3] = v.w;
        s  += v.x + v.y + v.z + v.w;
        s2 += v.x * v.x + v.y * v.y + v.z * v.z + v.w * v.w;
    }
    const int lane = t & 63, wid = t >> 6;
    for (int off = 32; off; off >>= 1) {
        s  += __shfl_xor(s,  off, 64);
        s2 += __shfl_xor(s2, off, 64);
    }
    if (lane == 0) { red[wid * 2] = s; red[wid * 2 + 1] = s2; }
    __syncthreads();
    if (t == 0) {
        float ts = 0.f, ts2 = 0.f;
        for (int w = 0; w < 8; w++) { ts += red[w * 2]; ts2 += red[w * 2 + 1]; }
        float mean = ts / (float)(CPG * HW);
        float var  = ts2 / (float)(CPG * HW) - mean * mean;
        red[16] = mean;
        red[17] = rsqrtf(var + EPS);
    }
    __syncthreads();
    const float mean = red[16], rstd = red[17];
    const int cbase = g * CPG;
    if (t < CPG) {
        float a = gamma[cbase + t] * rstd;
        lga[t] = a;
        lbe[t] = beta[cbase + t] - mean * a;
    }
    __syncthreads();

    u16* dst = (u16*)xnT + (size_t)b * HW * C_CH + cbase;
#pragma unroll 4
    for (int i = 0; i < 12; i++) {
        int k = i * 512 + t;
        int p = k / 6;
        int c = (k - p * 6) * 4;
        ushort4 u;
        u.x = f2bf(lds[(c + 0) * 1025 + p] * lga[c + 0] + lbe[c + 0]);
        u.y = f2bf(lds[(c + 1) * 1025 + p] * lga[c + 1] + lbe[c + 1]);
        u.z = f2bf(lds[(c + 2) * 1025 + p] * lga[c + 2] + lbe[c + 2]);
        u.w = f2bf(lds[(c + 3) * 1025 + p] * lga[c + 3] + lbe[c + 3]);
        *(ushort4*)(dst + (size_t)p * C_CH + c) = u;
    }
}

// ------------- row softmax over att [rows][768] bf16, in place (8 rows/block, 512 thr) -------------
__global__ __launch_bounds__(512) void softmax_kernel(__hip_bfloat16* __restrict__ att) {
    int row  = blockIdx.x * 8 + (threadIdx.x >> 6);
    int lane = threadIdx.x & 63;
    u16* p = (u16*)(att + (size_t)row * C_CH);
    float v[12];
    float m = -1e30f;
    for (int j = 0; j < 12; j++) {
        v[j] = bf2f(p[j * 64 + lane]);
        m = fmaxf(m, v[j]);
    }
    for (int off = 32; off; off >>= 1) m = fmaxf(m, __shfl_xor(m, off, 64));
    float s = 0.f;
    for (int j = 0; j < 12; j++) { v[j] = __expf(v[j] - m); s += v[j]; }
    for (int off = 32; off; off >>= 1) s += __shfl_xor(s, off, 64);
    float inv = 1.0f / s;
    for (int j = 0; j < 12; j++) p[j * 64 + lane] = f2bf(v[j] * inv);
}

// ---------------- NT GEMM 128x128 (R6-verified, 4 waves) — used for GEMM2 only ----------------
template<int OUT_F32>
__global__ __launch_bounds__(256, 2) void gemm_nt_kernel(
    const __hip_bfloat16* __restrict__ A, long sA,
    const __hip_bfloat16* __restrict__ B, long sB,
    void* __restrict__ Cout, long sC, int ldc,
    int K, float scale,
    const float* __restrict__ bias_row,
    const float* __restrict__ bias_col,
    const float* __restrict__ residual, long sR)
{
    __shared__ __hip_bfloat16 ldsA[128 * 64];
    __shared__ __hip_bfloat16 ldsB[128 * 64];
    int bxx, byy, bzz;
    xcd_remap(bxx, byy, bzz);
    const int t  = threadIdx.x;
    const int b  = bzz;
    const int m0 = byy * 128;
    const int n0 = bxx * 128;
    const int lane = t & 63;
    const int wid  = t >> 6;
    const int wm = wid >> 1, wn = wid & 1;
    const int lrow = lane & 15, lk = lane >> 4;

    const int srow   = t >> 3;
    const int schunk = t & 7;
    const int kphys  = (schunk ^ (srow & 7)) * 8;

    const __hip_bfloat16* aBase = A + (size_t)b * sA + (size_t)(m0 + srow) * K + kphys;
    const __hip_bfloat16* bBase = B + (size_t)b * sB + (size_t)(n0 + srow) * K + kphys;
    const int ldsDst = (t & ~63) * 8;

    f32x4 acc[4][4] = {};

    const int nk = K >> 6;
    for (int kt = 0; kt < nk; kt++) {
        __syncthreads();
        const __hip_bfloat16* ak = aBase + (size_t)kt * 64;
        const __hip_bfloat16* bk = bBase + (size_t)kt * 64;
        for (int r = 0; r < 4; r++)
            load_lds16(ak + (size_t)r * 32 * K, &ldsA[ldsDst + r * 2048]);
        for (int r = 0; r < 4; r++)
            load_lds16(bk + (size_t)r * 32 * K, &ldsB[ldsDst + r * 2048]);
        __syncthreads();
        for (int h = 0; h < 2; h++) {
            bf16x8 af[4], bfr[4];
            const int lc = h * 4 + lk;
            for (int i = 0; i < 4; i++) {
                int row = wm * 64 + i * 16 + lrow;
                int pc = lc ^ (row & 7);
                af[i] = *(const bf16x8*)&ldsA[row * 64 + pc * 8];
            }
            for (int i = 0; i < 4; i++) {
                int col = wn * 64 + i * 16 + lrow;
                int pc = lc ^ (col & 7);
                bfr[i] = *(const bf16x8*)&ldsB[col * 64 + pc * 8];
            }
            for (int i = 0; i < 4; i++)
                for (int j = 0; j < 4; j++)
                    acc[i][j] = __builtin_amdgcn_mfma_f32_16x16x32_bf16(
                        af[i], bfr[j], acc[i][j], 0, 0, 0);
        }
    }

    __hip_bfloat16* outB = (__hip_bfloat16*)Cout;
    float* outF = (float*)Cout;
    for (int i = 0; i < 4; i++)
        for (int j = 0; j < 4; j++) {
            int row = m0 + wm * 64 + i * 16 + lk * 4;
            int col = n0 + wn * 64 + j * 16 + lrow;
            f32x4 a = acc[i][j];
            for (int r = 0; r < 4; r++) {
                int rr = row + r;
                float v = a[r] * scale;
                if (bias_row) v += bias_row[rr];
                if (bias_col) v += bias_col[col];
                if (residual) v += residual[(size_t)b * sR + (size_t)rr * ldc + col];
                size_t off = (size_t)b * sC + (size_t)rr * ldc + col;
                if (OUT_F32) outF[off] = v;
                else         outB[off] = __float2bfloat16(v);
            }
        }
}

// ---------------- NT GEMM 256(M)x128(N), 512 thr / 8 waves — QKV (R8/R9/R11-verified) ----------------
__global__ __launch_bounds__(512, 2) void gemm_nt_qkv(
    const __hip_bfloat16* __restrict__ A,
    const __hip_bfloat16* __restrict__ B, long sB,
    __hip_bfloat16* __restrict__ Cout, long sC, int ldc,
    int K,
    const float* __restrict__ bias_row,
    __hip_bfloat16* __restrict__ vt_out, long sVT, int vt_start)
{
    __shared__ __hip_bfloat16 ldsA[256 * 64];
    __shared__ __hip_bfloat16 ldsB[128 * 64];
    int bxx, byy, bzz;
    xcd_remap(bxx, byy, bzz);
    const int t  = threadIdx.x;
    const int b  = bzz;
    const int m0 = byy * 256;
    const int n0 = bxx * 128;
    const int lane = t & 63;
    const int wid  = t >> 6;
    const int wm = wid >> 1;
    const int wn = wid & 1;
    const int lrow = lane & 15, lk = lane >> 4;

    const int srow  = t >> 3;
    const int kphys = ((t & 7) ^ (srow & 7)) * 8;
    const int dstW  = (t & ~63) * 8;

    const __hip_bfloat16* aBase = A + (size_t)(m0 + srow) * K + kphys;
    const __hip_bfloat16* bBase = B + (size_t)b * sB + (size_t)(n0 + srow) * K + kphys;

    f32x4 acc[4][4] = {};

    const int nk = K >> 6;
    for (int kt = 0; kt < nk; kt++) {
        __syncthreads();
        const __hip_bfloat16* ak = aBase + (size_t)kt * 64;
        const __hip_bfloat16* bk = bBase + (size_t)kt * 64;
#pragma unroll
        for (int l = 0; l < 4; l++)
            load_lds16(ak + (size_t)l * 64 * K, &ldsA[dstW + l * 4096]);
#pragma unroll
        for (int l = 0; l < 2; l++)
            load_lds16(bk + (size_t)l * 64 * K, &ldsB[dstW + l * 4096]);
        __syncthreads();
#pragma unroll
        for (int h = 0; h < 2; h++) {
            bf16x8 af[4], bfr[4];
            const int lc = h * 4 + lk;
#pragma unroll
            for (int i = 0; i < 4; i++) {
                int row = wm * 64 + i * 16 + lrow;
                af[i] = *(const bf16x8*)&ldsA[row * 64 + (lc ^ (row & 7)) * 8];
            }
#pragma unroll
            for (int j = 0; j < 4; j++) {
                int col = wn * 64 + j * 16 + lrow;
                bfr[j] = *(const bf16x8*)&ldsB[col * 64 + (lc ^ (col & 7)) * 8];
            }
#pragma unroll
            for (int i = 0; i < 4; i++)
#pragma unroll
                for (int j = 0; j < 4; j++)
                    acc[i][j] = __builtin_amdgcn_mfma_f32_16x16x32_bf16(
                        af[i], bfr[j], acc[i][j], 0, 0, 0);
        }
    }

    if (m0 >= vt_start) {
        __hip_bfloat16* vtp = vt_out + (size_t)b * sVT;
#pragma unroll
        for (int i = 0; i < 4; i++)
#pragma unroll
            for (int j = 0; j < 4; j++) {
                int row = m0 + wm * 64 + i * 16 + lk * 4;   // o
                int col = n0 + wn * 64 + j * 16 + lrow;     // p
                f32x4 a = acc[i][j];
                ushort4 u;
                u.x = f2bf(a[0] + bias_row[row + 0]);
                u.y = f2bf(a[1] + bias_row[row + 1]);
                u.z = f2bf(a[2] + bias_row[row + 2]);
                u.w = f2bf(a[3] + bias_row[row + 3]);
                *(ushort4*)(vtp + (size_t)col * C_CH + (row - vt_start)) = u;
            }
        return;
    }

#pragma unroll
    for (int i = 0; i < 4; i++)
#pragma unroll
        for (int j = 0; j < 4; j++) {
            int row = m0 + wm * 64 + i * 16 + lk * 4;
            int col = n0 + wn * 64 + j * 16 + lrow;
            f32x4 a = acc[i][j];
#pragma unroll
            for (int r = 0; r < 4; r++) {
                int rr = row + r;
                Cout[(size_t)b * sC + (size_t)rr * ldc + col] =
                    __float2bfloat16(a[r] + bias_row[rr]);
            }
        }
}

// ---------------- GEMM3 (PV): outT[b,p,i] = sum_j vT[b,p,j] * att[b,i,j] (R11-verified) ----------------
__global__ __launch_bounds__(512, 2) void gemm3_pv(
    const __hip_bfloat16* __restrict__ vT,
    const __hip_bfloat16* __restrict__ att,
    __hip_bfloat16* __restrict__ outT)
{
    __shared__ __hip_bfloat16 ldsA[256 * 64];
    __shared__ __hip_bfloat16 ldsB[128 * 64];
    int bxx, byy, bzz;
    xcd_remap(bxx, byy, bzz);
    const int t  = threadIdx.x;
    const int b  = bzz;
    const int m0 = byy * 256;          // p tile
    const int n0 = bxx * 128;          // i tile
    const int lane = t & 63;
    const int wid  = t >> 6;
    const int wm = wid >> 1;
    const int wn = wid & 1;
    const int lrow = lane & 15, lk = lane >> 4;

    const int srow  = t >> 3;
    const int kphys = ((t & 7) ^ (srow & 7)) * 8;
    const int dstW  = (t & ~63) * 8;

    const __hip_bfloat16* aBase = vT  + (size_t)b * (HW * C_CH)   + (size_t)(m0 + srow) * C_CH + kphys;
    const __hip_bfloat16* bBase = att + (size_t)b * (C_CH * C_CH) + (size_t)(n0 + srow) * C_CH + kphys;

    f32x4 acc[4][4] = {};

    for (int kt = 0; kt < C_CH / 64; kt++) {
        __syncthreads();
        const __hip_bfloat16* ak = aBase + (size_t)kt * 64;
        const __hip_bfloat16* bk = bBase + (size_t)kt * 64;
#pragma unroll
        for (int l = 0; l < 4; l++)
            load_lds16(ak + (size_t)l * 64 * C_CH, &ldsA[dstW + l * 4096]);
#pragma unroll
        for (int l = 0; l < 2; l++)
            load_lds16(bk + (size_t)l * 64 * C_CH, &ldsB[dstW + l * 4096]);
        __syncthreads();
#pragma unroll
        for (int h = 0; h < 2; h++) {
            bf16x8 af[4], bfr[4];
            const int lc = h * 4 + lk;
#pragma unroll
            for (int i = 0; i < 4; i++) {
                int row = wm * 64 + i * 16 + lrow;
                af[i] = *(const bf16x8*)&ldsA[row * 64 + (lc ^ (row & 7)) * 8];
            }
#pragma unroll
            for (int j = 0; j < 4; j++) {
                int col = wn * 64 + j * 16 + lrow;
                bfr[j] = *(const bf16x8*)&ldsB[col * 64 + (lc ^ (col & 7)) * 8];
            }
#pragma unroll
            for (int i = 0; i < 4; i++)
#pragma unroll
                for (int j = 0; j < 4; j++)
                    acc[i][j] = __builtin_amdgcn_mfma_f32_16x16x32_bf16(
                        af[i], bfr[j], acc[i][j], 0, 0, 0);
        }
    }

#pragma unroll
    for (int i = 0; i < 4; i++)
#pragma unroll
        for (int j = 0; j < 4; j++) {
            int row = m0 + wm * 64 + i * 16 + lk * 4;   // p
            int col = n0 + wn * 64 + j * 16 + lrow;     // i
            f32x4 a = acc[i][j];
#pragma unroll
            for (int r = 0; r < 4; r++)
                outT[(size_t)b * (HW * C_CH) + (size_t)(row + r) * C_CH + col] =
                    __float2bfloat16(a[r]);
        }
}

// ------------- GEMM4 (proj): out[b,o,p] = w_out·outT^T + b_out + x (R11-verified) -------------
__global__ __launch_bounds__(512, 2) void gemm4_proj(
    const __hip_bfloat16* __restrict__ wo,
    const __hip_bfloat16* __restrict__ outT,
    const float* __restrict__ b_out,
    const float* __restrict__ x,
    float* __restrict__ out)
{
    __shared__ __hip_bfloat16 ldsA[256 * 64];
    __shared__ __hip_bfloat16 ldsB[128 * 64];
    int bxx, byy, bzz;
    xcd_remap(bxx, byy, bzz);
    const int t  = threadIdx.x;
    const int b  = bzz;
    const int m0 = byy * 256;          // o tile
    const int n0 = bxx * 128;          // p tile
    const int lane = t & 63;
    const int wid  = t >> 6;
    const int wm = wid >> 1;
    const int wn = wid & 1;
    const int lrow = lane & 15, lk = lane >> 4;

    const int srow  = t >> 3;
    const int kphys = ((t & 7) ^ (srow & 7)) * 8;
    const int dstW  = (t & ~63) * 8;

    const __hip_bfloat16* aBase = wo   + (size_t)(m0 + srow) * C_CH + kphys;
    const __hip_bfloat16* bBase = outT + (size_t)b * (HW * C_CH) + (size_t)(n0 + srow) * C_CH + kphys;

    f32x4 acc[4][4] = {};

    for (int kt = 0; kt < C_CH / 64; kt++) {
        __syncthreads();
        const __hip_bfloat16* ak = aBase + (size_t)kt * 64;
        const __hip_bfloat16* bk = bBase + (size_t)kt * 64;
#pragma unroll
        for (int l = 0; l < 4; l++)
            load_lds16(ak + (size_t)l * 64 * C_CH, &ldsA[dstW + l * 4096]);
#pragma unroll
        for (int l = 0; l < 2; l++)
            load_lds16(bk + (size_t)l * 64 * C_CH, &ldsB[dstW + l * 4096]);
        __syncthreads();
#pragma unroll
        for (int h = 0; h < 2; h++) {
            bf16x8 af[4], bfr[4];
            const int lc = h * 4 + lk;
#pragma unroll
            for (int i = 0; i < 4; i++) {
                int row = wm * 64 + i * 16 + lrow;
                af[i] = *(const bf16x8*)&ldsA[row * 64 + (lc ^ (row & 7)) * 8];
            }
#pragma unroll
            for (int j = 0; j < 4; j++) {
                int col = wn * 64 + j * 16 + lrow;
                bfr[j] = *(const bf16x8*)&ldsB[col * 64 + (lc ^ (col & 7)) * 8];
            }
#pragma unroll
            for (int i = 0; i < 4; i++)
#pragma unroll
                for (int j = 0; j < 4; j++)
                    acc[i][j] = __builtin_amdgcn_mfma_f32_16x16x32_bf16(
                        af[i], bfr[j], acc[i][j], 0, 0, 0);
        }
    }

#pragma unroll
    for (int i = 0; i < 4; i++)
#pragma unroll
        for (int j = 0; j < 4; j++) {
            int row = m0 + wm * 64 + i * 16 + lk * 4;   // o
            int col = n0 + wn * 64 + j * 16 + lrow;     // p
            f32x4 a = acc[i][j];
#pragma unroll
            for (int r = 0; r < 4; r++) {
                size_t off = (size_t)b * (C_CH * HW) + (size_t)(row + r) * HW + col;
                out[off] = a[r] + b_out[row + r] + x[off];
            }
        }
}

extern "C" void kernel_launch(void* const* d_in, const int* in_sizes, int n_in,
                              void* d_out, int out_size, void* d_ws, size_t ws_size,
                              hipStream_t stream) {
    const float* x     = (const float*)d_in[0];
    const float* gamma = (const float*)d_in[1];
    const float* beta  = (const float*)d_in[2];
    const float* w_qkv = (const float*)d_in[3];
    const float* b_qkv = (const float*)d_in[4];
    const float* w_out = (const float*)d_in[5];
    const float* b_out = (const float*)d_in[6];

    char* ws = (char*)d_ws;
    size_t off = 0;
    auto alloc = [&](size_t bytes) {
        void* p = ws + off;
        off += (bytes + 255) & ~(size_t)255;
        return p;
    };
    __hip_bfloat16* xnT   = (__hip_bfloat16*)alloc((size_t)BATCH * HW * C_CH * 2);
    __hip_bfloat16* wqkvB = (__hip_bfloat16*)alloc((size_t)3 * C_CH * C_CH * 2);
    __hip_bfloat16* woutB = (__hip_bfloat16*)alloc((size_t)C_CH * C_CH * 2);
    __hip_bfloat16* qk    = (__hip_bfloat16*)alloc((size_t)BATCH * 2 * C_CH * HW * 2);
    __hip_bfloat16* vT    = (__hip_bfloat16*)alloc((size_t)BATCH * HW * C_CH * 2);
    __hip_bfloat16* att   = (__hip_bfloat16*)alloc((size_t)BATCH * C_CH * C_CH * 2);
    __hip_bfloat16* outT  = (__hip_bfloat16*)alloc((size_t)BATCH * HW * C_CH * 2);

    // 1) cast both weight arrays to bf16, one launch
    {
        int total4 = N4_QKV + N4_OUT;
        cast_weights_kernel<<<(total4 + 255) / 256, 256, 0, stream>>>(
            (const float4*)w_qkv, (const float4*)w_out,
            (ushort4*)wqkvB, (ushort4*)woutB);
    }
    // 2) Fused GroupNorm (stats + normalize + transpose, single pass over x)
    gn_fused_kernel<<<BATCH * NG, 512, 0, stream>>>(x, gamma, beta, xnT);

    // 3) QKV GEMM (merged, 256x128): M=2304, N=1024, K=768.
    //    o < 1536 -> qk[b,o,p]; o >= 1536 -> transposed into vT[b,p,o-1536].
    gemm_nt_qkv<<<dim3(HW / 128, 2304 / 256, BATCH), 512, 0, stream>>>(
        wqkvB, xnT, (long)HW * C_CH, qk, (long)2 * C_CH * HW, HW,
        C_CH, b_qkv, vT, (long)HW * C_CH, 2 * C_CH);

    // 4) GEMM2: att[b,i,j] = q.k^T * hw^-0.5  (M=768,N=768,K=1024), 128² kernel
    gemm_nt_kernel<0><<<dim3(C_CH / 128, C_CH / 128, BATCH), 256, 0, stream>>>(
        qk, (long)2 * C_CH * HW, qk + (size_t)C_CH * HW, (long)2 * C_CH * HW,
        att, (long)C_CH * C_CH, C_CH,
        HW, 1.0f / 32.0f, nullptr, nullptr, nullptr, 0);

    // 5) softmax rows (8 rows per 512-thread block)
    softmax_kernel<<<(BATCH * C_CH) / 8, 512, 0, stream>>>(att);

    // 6) GEMM3: outT[b,p,i] = vT . att^T  (M=1024,N=768,K=768), specialized 256x128
    gemm3_pv<<<dim3(C_CH / 128, HW / 256, BATCH), 512, 0, stream>>>(vT, att, outT);

    // 7) GEMM4: out[b,o,p] = w_out . outT^T + b_out + x  (M=768,N=1024,K=768),
    //    specialized 256x128, f32 out + residual
    gemm4_proj<<<dim3(HW / 128, C_CH / 256, BATCH), 512, 0, stream>>>(
        woutB, outT, b_out, x, (float*)d_out);
}

// Round 13
// 187.999 us; speedup vs baseline: 1.0192x; 1.0192x over previous
//
#include <hip/hip_runtime.h>
#include <hip/hip_bf16.h>

#define HW 1024
#define C_CH 768
#define BATCH 16
#define NG 32
#define CPG 24
#define EPS 1e-5f

typedef __attribute__((ext_vector_type(8))) short bf16x8;
typedef __attribute__((ext_vector_type(4))) float f32x4;
typedef unsigned short u16;
typedef unsigned int u32;

typedef const __attribute__((address_space(1))) void* gas_ptr;
typedef __attribute__((address_space(3))) void* las_ptr;

__device__ __forceinline__ void load_lds16(const void* g, void* l) {
    __builtin_amdgcn_global_load_lds((gas_ptr)g, (las_ptr)l, 16, 0, 0);
}

__device__ __forceinline__ u16 f2bf(float f) {
    __hip_bfloat16 h = __float2bfloat16(f);
    return *(u16*)&h;
}
__device__ __forceinline__ float bf2f(u16 u) {
    return __uint_as_float(((u32)u) << 16);
}

// Bijective XCD-chunked swizzle (R6-verified win).
__device__ __forceinline__ void xcd_remap(int& bx, int& by, int& bz) {
    const int nbx = gridDim.x, nby = gridDim.y;
    const int nwg = nbx * nby * gridDim.z;
    int bid = blockIdx.x + nbx * (blockIdx.y + nby * blockIdx.z);
    if ((nwg & 7) == 0) {
        const int q = nwg >> 3;
        bid = (bid & 7) * q + (bid >> 3);
    }
    bx = bid % nbx;
    int t2 = bid / nbx;
    by = t2 % nby;
    bz = t2 / nby;
}

// ---------------- merged weight cast f32 -> bf16 (both arrays, ONE launch) ----------------
#define N4_QKV ((3 * C_CH * C_CH) / 4)
#define N4_OUT ((C_CH * C_CH) / 4)
__global__ __launch_bounds__(256) void cast_weights_kernel(const float4* __restrict__ wqkv,
                                                           const float4* __restrict__ wout,
                                                           ushort4* __restrict__ outQ,
                                                           ushort4* __restrict__ outO) {
    int i = blockIdx.x * 256 + threadIdx.x;
    const float4* src;
    ushort4* dst;
    int idx;
    if (i < N4_QKV) { src = wqkv; dst = outQ; idx = i; }
    else if (i < N4_QKV + N4_OUT) { src = wout; dst = outO; idx = i - N4_QKV; }
    else return;
    float4 v = src[idx];
    ushort4 u;
    u.x = f2bf(v.x); u.y = f2bf(v.y); u.z = f2bf(v.z); u.w = f2bf(v.w);
    dst[idx] = u;
}

// ---------- Fused GroupNorm: stats + normalize + transpose in ONE pass (R9-verified) ----------
__global__ __launch_bounds__(512) void gn_fused_kernel(const float* __restrict__ x,
                                                       const float* __restrict__ gamma,
                                                       const float* __restrict__ beta,
                                                       __hip_bfloat16* __restrict__ xnT) {
    __shared__ float lds[24 * 1025];
    __shared__ float red[18];
    __shared__ float lga[24], lbe[24];
    const int bg = blockIdx.x;
    const int b = bg >> 5, g = bg & 31;
    const int t = threadIdx.x;
    const float4* src = (const float4*)(x + (size_t)bg * (CPG * HW));

    float s = 0.f, s2 = 0.f;
#pragma unroll 4
    for (int i = 0; i < 12; i++) {
        int fl4 = i * 512 + t;
        float4 v = src[fl4];
        int flat = fl4 * 4;
        int c = flat >> 10, p = flat & 1023;
        float* d = &lds[c * 1025 + p];
        d[0] = v.x; d[1] = v.y; d[2] = v.z; d[3] = v.w;
        s  += v.x + v.y + v.z + v.w;
        s2 += v.x * v.x + v.y * v.y + v.z * v.z + v.w * v.w;
    }
    const int lane = t & 63, wid = t >> 6;
    for (int off = 32; off; off >>= 1) {
        s  += __shfl_xor(s,  off, 64);
        s2 += __shfl_xor(s2, off, 64);
    }
    if (lane == 0) { red[wid * 2] = s; red[wid * 2 + 1] = s2; }
    __syncthreads();
    if (t == 0) {
        float ts = 0.f, ts2 = 0.f;
        for (int w = 0; w < 8; w++) { ts += red[w * 2]; ts2 += red[w * 2 + 1]; }
        float mean = ts / (float)(CPG * HW);
        float var  = ts2 / (float)(CPG * HW) - mean * mean;
        red[16] = mean;
        red[17] = rsqrtf(var + EPS);
    }
    __syncthreads();
    const float mean = red[16], rstd = red[17];
    const int cbase = g * CPG;
    if (t < CPG) {
        float a = gamma[cbase + t] * rstd;
        lga[t] = a;
        lbe[t] = beta[cbase + t] - mean * a;
    }
    __syncthreads();

    u16* dst = (u16*)xnT + (size_t)b * HW * C_CH + cbase;
#pragma unroll 4
    for (int i = 0; i < 12; i++) {
        int k = i * 512 + t;
        int p = k / 6;
        int c = (k - p * 6) * 4;
        ushort4 u;
        u.x = f2bf(lds[(c + 0) * 1025 + p] * lga[c + 0] + lbe[c + 0]);
        u.y = f2bf(lds[(c + 1) * 1025 + p] * lga[c + 1] + lbe[c + 1]);
        u.z = f2bf(lds[(c + 2) * 1025 + p] * lga[c + 2] + lbe[c + 2]);
        u.w = f2bf(lds[(c + 3) * 1025 + p] * lga[c + 3] + lbe[c + 3]);
        *(ushort4*)(dst + (size_t)p * C_CH + c) = u;
    }
}

// ------------- row softmax over att [rows][768] bf16, in place (8 rows/block, 512 thr) -------------
__global__ __launch_bounds__(512) void softmax_kernel(__hip_bfloat16* __restrict__ att) {
    int row  = blockIdx.x * 8 + (threadIdx.x >> 6);
    int lane = threadIdx.x & 63;
    u16* p = (u16*)(att + (size_t)row * C_CH);
    float v[12];
    float m = -1e30f;
    for (int j = 0; j < 12; j++) {
        v[j] = bf2f(p[j * 64 + lane]);
        m = fmaxf(m, v[j]);
    }
    for (int off = 32; off; off >>= 1) m = fmaxf(m, __shfl_xor(m, off, 64));
    float s = 0.f;
    for (int j = 0; j < 12; j++) { v[j] = __expf(v[j] - m); s += v[j]; }
    for (int off = 32; off; off >>= 1) s += __shfl_xor(s, off, 64);
    float inv = 1.0f / s;
    for (int j = 0; j < 12; j++) p[j * 64 + lane] = f2bf(v[j] * inv);
}

// ---------------- NT GEMM 256(M)x128(N), 512 thr / 8 waves — QKV (R8/R9/R11-verified) ----------------
__global__ __launch_bounds__(512, 2) void gemm_nt_qkv(
    const __hip_bfloat16* __restrict__ A,
    const __hip_bfloat16* __restrict__ B, long sB,
    __hip_bfloat16* __restrict__ Cout, long sC, int ldc,
    int K,
    const float* __restrict__ bias_row,
    __hip_bfloat16* __restrict__ vt_out, long sVT, int vt_start)
{
    __shared__ __hip_bfloat16 ldsA[256 * 64];
    __shared__ __hip_bfloat16 ldsB[128 * 64];
    int bxx, byy, bzz;
    xcd_remap(bxx, byy, bzz);
    const int t  = threadIdx.x;
    const int b  = bzz;
    const int m0 = byy * 256;
    const int n0 = bxx * 128;
    const int lane = t & 63;
    const int wid  = t >> 6;
    const int wm = wid >> 1;
    const int wn = wid & 1;
    const int lrow = lane & 15, lk = lane >> 4;

    const int srow  = t >> 3;
    const int kphys = ((t & 7) ^ (srow & 7)) * 8;
    const int dstW  = (t & ~63) * 8;

    const __hip_bfloat16* aBase = A + (size_t)(m0 + srow) * K + kphys;
    const __hip_bfloat16* bBase = B + (size_t)b * sB + (size_t)(n0 + srow) * K + kphys;

    f32x4 acc[4][4] = {};

    const int nk = K >> 6;
    for (int kt = 0; kt < nk; kt++) {
        __syncthreads();
        const __hip_bfloat16* ak = aBase + (size_t)kt * 64;
        const __hip_bfloat16* bk = bBase + (size_t)kt * 64;
#pragma unroll
        for (int l = 0; l < 4; l++)
            load_lds16(ak + (size_t)l * 64 * K, &ldsA[dstW + l * 4096]);
#pragma unroll
        for (int l = 0; l < 2; l++)
            load_lds16(bk + (size_t)l * 64 * K, &ldsB[dstW + l * 4096]);
        __syncthreads();
#pragma unroll
        for (int h = 0; h < 2; h++) {
            bf16x8 af[4], bfr[4];
            const int lc = h * 4 + lk;
#pragma unroll
            for (int i = 0; i < 4; i++) {
                int row = wm * 64 + i * 16 + lrow;
                af[i] = *(const bf16x8*)&ldsA[row * 64 + (lc ^ (row & 7)) * 8];
            }
#pragma unroll
            for (int j = 0; j < 4; j++) {
                int col = wn * 64 + j * 16 + lrow;
                bfr[j] = *(const bf16x8*)&ldsB[col * 64 + (lc ^ (col & 7)) * 8];
            }
#pragma unroll
            for (int i = 0; i < 4; i++)
#pragma unroll
                for (int j = 0; j < 4; j++)
                    acc[i][j] = __builtin_amdgcn_mfma_f32_16x16x32_bf16(
                        af[i], bfr[j], acc[i][j], 0, 0, 0);
        }
    }

    if (m0 >= vt_start) {
        __hip_bfloat16* vtp = vt_out + (size_t)b * sVT;
#pragma unroll
        for (int i = 0; i < 4; i++)
#pragma unroll
            for (int j = 0; j < 4; j++) {
                int row = m0 + wm * 64 + i * 16 + lk * 4;   // o
                int col = n0 + wn * 64 + j * 16 + lrow;     // p
                f32x4 a = acc[i][j];
                ushort4 u;
                u.x = f2bf(a[0] + bias_row[row + 0]);
                u.y = f2bf(a[1] + bias_row[row + 1]);
                u.z = f2bf(a[2] + bias_row[row + 2]);
                u.w = f2bf(a[3] + bias_row[row + 3]);
                *(ushort4*)(vtp + (size_t)col * C_CH + (row - vt_start)) = u;
            }
        return;
    }

#pragma unroll
    for (int i = 0; i < 4; i++)
#pragma unroll
        for (int j = 0; j < 4; j++) {
            int row = m0 + wm * 64 + i * 16 + lk * 4;
            int col = n0 + wn * 64 + j * 16 + lrow;
            f32x4 a = acc[i][j];
#pragma unroll
            for (int r = 0; r < 4; r++) {
                int rr = row + r;
                Cout[(size_t)b * sC + (size_t)rr * ldc + col] =
                    __float2bfloat16(a[r] + bias_row[rr]);
            }
        }
}

// ---------------- GEMM2 (QK^T): att[b,i,j] = (1/32) * sum_p q[b,i,p] * k[b,j,p] ----------------
// Hand-specialized copy of the proven 256x128 inner loop; hardcoded strides.
// q = qk[b, 0..768), k = qk[b, 768..1536); rows at stride HW=1024, K=1024 (16 K-steps).
// M=768 (i, 256-tiles), N=768 (j, 128-tiles). Grid (6, 3, 16) = 288 blocks.
__global__ __launch_bounds__(512, 2) void gemm2_qk(
    const __hip_bfloat16* __restrict__ qk,
    __hip_bfloat16* __restrict__ att)
{
    __shared__ __hip_bfloat16 ldsA[256 * 64];
    __shared__ __hip_bfloat16 ldsB[128 * 64];
    int bxx, byy, bzz;
    xcd_remap(bxx, byy, bzz);
    const int t  = threadIdx.x;
    const int b  = bzz;
    const int m0 = byy * 256;          // i tile
    const int n0 = bxx * 128;          // j tile
    const int lane = t & 63;
    const int wid  = t >> 6;
    const int wm = wid >> 1;
    const int wn = wid & 1;
    const int lrow = lane & 15, lk = lane >> 4;

    const int srow  = t >> 3;
    const int kphys = ((t & 7) ^ (srow & 7)) * 8;
    const int dstW  = (t & ~63) * 8;

    const __hip_bfloat16* aBase = qk + (size_t)b * (2 * C_CH * HW)
                                     + (size_t)(m0 + srow) * HW + kphys;          // q rows
    const __hip_bfloat16* bBase = qk + (size_t)b * (2 * C_CH * HW) + (size_t)C_CH * HW
                                     + (size_t)(n0 + srow) * HW + kphys;          // k rows

    f32x4 acc[4][4] = {};

    for (int kt = 0; kt < HW / 64; kt++) {
        __syncthreads();
        const __hip_bfloat16* ak = aBase + (size_t)kt * 64;
        const __hip_bfloat16* bk = bBase + (size_t)kt * 64;
#pragma unroll
        for (int l = 0; l < 4; l++)
            load_lds16(ak + (size_t)l * 64 * HW, &ldsA[dstW + l * 4096]);
#pragma unroll
        for (int l = 0; l < 2; l++)
            load_lds16(bk + (size_t)l * 64 * HW, &ldsB[dstW + l * 4096]);
        __syncthreads();
#pragma unroll
        for (int h = 0; h < 2; h++) {
            bf16x8 af[4], bfr[4];
            const int lc = h * 4 + lk;
#pragma unroll
            for (int i = 0; i < 4; i++) {
                int row = wm * 64 + i * 16 + lrow;
                af[i] = *(const bf16x8*)&ldsA[row * 64 + (lc ^ (row & 7)) * 8];
            }
#pragma unroll
            for (int j = 0; j < 4; j++) {
                int col = wn * 64 + j * 16 + lrow;
                bfr[j] = *(const bf16x8*)&ldsB[col * 64 + (lc ^ (col & 7)) * 8];
            }
#pragma unroll
            for (int i = 0; i < 4; i++)
#pragma unroll
                for (int j = 0; j < 4; j++)
                    acc[i][j] = __builtin_amdgcn_mfma_f32_16x16x32_bf16(
                        af[i], bfr[j], acc[i][j], 0, 0, 0);
        }
    }

#pragma unroll
    for (int i = 0; i < 4; i++)
#pragma unroll
        for (int j = 0; j < 4; j++) {
            int row = m0 + wm * 64 + i * 16 + lk * 4;   // i
            int col = n0 + wn * 64 + j * 16 + lrow;     // j
            f32x4 a = acc[i][j];
#pragma unroll
            for (int r = 0; r < 4; r++)
                att[(size_t)b * (C_CH * C_CH) + (size_t)(row + r) * C_CH + col] =
                    __float2bfloat16(a[r] * (1.0f / 32.0f));
        }
}

// ---------------- GEMM3 (PV): outT[b,p,i] = sum_j vT[b,p,j] * att[b,i,j] (R11-verified) ----------------
__global__ __launch_bounds__(512, 2) void gemm3_pv(
    const __hip_bfloat16* __restrict__ vT,
    const __hip_bfloat16* __restrict__ att,
    __hip_bfloat16* __restrict__ outT)
{
    __shared__ __hip_bfloat16 ldsA[256 * 64];
    __shared__ __hip_bfloat16 ldsB[128 * 64];
    int bxx, byy, bzz;
    xcd_remap(bxx, byy, bzz);
    const int t  = threadIdx.x;
    const int b  = bzz;
    const int m0 = byy * 256;          // p tile
    const int n0 = bxx * 128;          // i tile
    const int lane = t & 63;
    const int wid  = t >> 6;
    const int wm = wid >> 1;
    const int wn = wid & 1;
    const int lrow = lane & 15, lk = lane >> 4;

    const int srow  = t >> 3;
    const int kphys = ((t & 7) ^ (srow & 7)) * 8;
    const int dstW  = (t & ~63) * 8;

    const __hip_bfloat16* aBase = vT  + (size_t)b * (HW * C_CH)   + (size_t)(m0 + srow) * C_CH + kphys;
    const __hip_bfloat16* bBase = att + (size_t)b * (C_CH * C_CH) + (size_t)(n0 + srow) * C_CH + kphys;

    f32x4 acc[4][4] = {};

    for (int kt = 0; kt < C_CH / 64; kt++) {
        __syncthreads();
        const __hip_bfloat16* ak = aBase + (size_t)kt * 64;
        const __hip_bfloat16* bk = bBase + (size_t)kt * 64;
#pragma unroll
        for (int l = 0; l < 4; l++)
            load_lds16(ak + (size_t)l * 64 * C_CH, &ldsA[dstW + l * 4096]);
#pragma unroll
        for (int l = 0; l < 2; l++)
            load_lds16(bk + (size_t)l * 64 * C_CH, &ldsB[dstW + l * 4096]);
        __syncthreads();
#pragma unroll
        for (int h = 0; h < 2; h++) {
            bf16x8 af[4], bfr[4];
            const int lc = h * 4 + lk;
#pragma unroll
            for (int i = 0; i < 4; i++) {
                int row = wm * 64 + i * 16 + lrow;
                af[i] = *(const bf16x8*)&ldsA[row * 64 + (lc ^ (row & 7)) * 8];
            }
#pragma unroll
            for (int j = 0; j < 4; j++) {
                int col = wn * 64 + j * 16 + lrow;
                bfr[j] = *(const bf16x8*)&ldsB[col * 64 + (lc ^ (col & 7)) * 8];
            }
#pragma unroll
            for (int i = 0; i < 4; i++)
#pragma unroll
                for (int j = 0; j < 4; j++)
                    acc[i][j] = __builtin_amdgcn_mfma_f32_16x16x32_bf16(
                        af[i], bfr[j], acc[i][j], 0, 0, 0);
        }
    }

#pragma unroll
    for (int i = 0; i < 4; i++)
#pragma unroll
        for (int j = 0; j < 4; j++) {
            int row = m0 + wm * 64 + i * 16 + lk * 4;   // p
            int col = n0 + wn * 64 + j * 16 + lrow;     // i
            f32x4 a = acc[i][j];
#pragma unroll
            for (int r = 0; r < 4; r++)
                outT[(size_t)b * (HW * C_CH) + (size_t)(row + r) * C_CH + col] =
                    __float2bfloat16(a[r]);
        }
}

// ------------- GEMM4 (proj): out[b,o,p] = w_out·outT^T + b_out + x (R11-verified) -------------
__global__ __launch_bounds__(512, 2) void gemm4_proj(
    const __hip_bfloat16* __restrict__ wo,
    const __hip_bfloat16* __restrict__ outT,
    const float* __restrict__ b_out,
    const float* __restrict__ x,
    float* __restrict__ out)
{
    __shared__ __hip_bfloat16 ldsA[256 * 64];
    __shared__ __hip_bfloat16 ldsB[128 * 64];
    int bxx, byy, bzz;
    xcd_remap(bxx, byy, bzz);
    const int t  = threadIdx.x;
    const int b  = bzz;
    const int m0 = byy * 256;          // o tile
    const int n0 = bxx * 128;          // p tile
    const int lane = t & 63;
    const int wid  = t >> 6;
    const int wm = wid >> 1;
    const int wn = wid & 1;
    const int lrow = lane & 15, lk = lane >> 4;

    const int srow  = t >> 3;
    const int kphys = ((t & 7) ^ (srow & 7)) * 8;
    const int dstW  = (t & ~63) * 8;

    const __hip_bfloat16* aBase = wo   + (size_t)(m0 + srow) * C_CH + kphys;
    const __hip_bfloat16* bBase = outT + (size_t)b * (HW * C_CH) + (size_t)(n0 + srow) * C_CH + kphys;

    f32x4 acc[4][4] = {};

    for (int kt = 0; kt < C_CH / 64; kt++) {
        __syncthreads();
        const __hip_bfloat16* ak = aBase + (size_t)kt * 64;
        const __hip_bfloat16* bk = bBase + (size_t)kt * 64;
#pragma unroll
        for (int l = 0; l < 4; l++)
            load_lds16(ak + (size_t)l * 64 * C_CH, &ldsA[dstW + l * 4096]);
#pragma unroll
        for (int l = 0; l < 2; l++)
            load_lds16(bk + (size_t)l * 64 * C_CH, &ldsB[dstW + l * 4096]);
        __syncthreads();
#pragma unroll
        for (int h = 0; h < 2; h++) {
            bf16x8 af[4], bfr[4];
            const int lc = h * 4 + lk;
#pragma unroll
            for (int i = 0; i < 4; i++) {
                int row = wm * 64 + i * 16 + lrow;
                af[i] = *(const bf16x8*)&ldsA[row * 64 + (lc ^ (row & 7)) * 8];
            }
#pragma unroll
            for (int j = 0; j < 4; j++) {
                int col = wn * 64 + j * 16 + lrow;
                bfr[j] = *(const bf16x8*)&ldsB[col * 64 + (lc ^ (col & 7)) * 8];
            }
#pragma unroll
            for (int i = 0; i < 4; i++)
#pragma unroll
                for (int j = 0; j < 4; j++)
                    acc[i][j] = __builtin_amdgcn_mfma_f32_16x16x32_bf16(
                        af[i], bfr[j], acc[i][j], 0, 0, 0);
        }
    }

#pragma unroll
    for (int i = 0; i < 4; i++)
#pragma unroll
        for (int j = 0; j < 4; j++) {
            int row = m0 + wm * 64 + i * 16 + lk * 4;   // o
            int col = n0 + wn * 64 + j * 16 + lrow;     // p
            f32x4 a = acc[i][j];
#pragma unroll
            for (int r = 0; r < 4; r++) {
                size_t off = (size_t)b * (C_CH * HW) + (size_t)(row + r) * HW + col;
                out[off] = a[r] + b_out[row + r] + x[off];
            }
        }
}

extern "C" void kernel_launch(void* const* d_in, const int* in_sizes, int n_in,
                              void* d_out, int out_size, void* d_ws, size_t ws_size,
                              hipStream_t stream) {
    const float* x     = (const float*)d_in[0];
    const float* gamma = (const float*)d_in[1];
    const float* beta  = (const float*)d_in[2];
    const float* w_qkv = (const float*)d_in[3];
    const float* b_qkv = (const float*)d_in[4];
    const float* w_out = (const float*)d_in[5];
    const float* b_out = (const float*)d_in[6];

    char* ws = (char*)d_ws;
    size_t off = 0;
    auto alloc = [&](size_t bytes) {
        void* p = ws + off;
        off += (bytes + 255) & ~(size_t)255;
        return p;
    };
    __hip_bfloat16* xnT   = (__hip_bfloat16*)alloc((size_t)BATCH * HW * C_CH * 2);
    __hip_bfloat16* wqkvB = (__hip_bfloat16*)alloc((size_t)3 * C_CH * C_CH * 2);
    __hip_bfloat16* woutB = (__hip_bfloat16*)alloc((size_t)C_CH * C_CH * 2);
    __hip_bfloat16* qk    = (__hip_bfloat16*)alloc((size_t)BATCH * 2 * C_CH * HW * 2);
    __hip_bfloat16* vT    = (__hip_bfloat16*)alloc((size_t)BATCH * HW * C_CH * 2);
    __hip_bfloat16* att   = (__hip_bfloat16*)alloc((size_t)BATCH * C_CH * C_CH * 2);
    __hip_bfloat16* outT  = (__hip_bfloat16*)alloc((size_t)BATCH * HW * C_CH * 2);

    // 1) cast both weight arrays to bf16, one launch
    {
        int total4 = N4_QKV + N4_OUT;
        cast_weights_kernel<<<(total4 + 255) / 256, 256, 0, stream>>>(
            (const float4*)w_qkv, (const float4*)w_out,
            (ushort4*)wqkvB, (ushort4*)woutB);
    }
    // 2) Fused GroupNorm (stats + normalize + transpose, single pass over x)
    gn_fused_kernel<<<BATCH * NG, 512, 0, stream>>>(x, gamma, beta, xnT);

    // 3) QKV GEMM (merged, 256x128): M=2304, N=1024, K=768.
    //    o < 1536 -> qk[b,o,p]; o >= 1536 -> transposed into vT[b,p,o-1536].
    gemm_nt_qkv<<<dim3(HW / 128, 2304 / 256, BATCH), 512, 0, stream>>>(
        wqkvB, xnT, (long)HW * C_CH, qk, (long)2 * C_CH * HW, HW,
        C_CH, b_qkv, vT, (long)HW * C_CH, 2 * C_CH);

    // 4) GEMM2: att[b,i,j] = q.k^T * hw^-0.5  (M=768,N=768,K=1024), specialized 256x128
    gemm2_qk<<<dim3(C_CH / 128, C_CH / 256, BATCH), 512, 0, stream>>>(qk, att);

    // 5) softmax rows (8 rows per 512-thread block)
    softmax_kernel<<<(BATCH * C_CH) / 8, 512, 0, stream>>>(att);

    // 6) GEMM3: outT[b,p,i] = vT . att^T  (M=1024,N=768,K=768), specialized 256x128
    gemm3_pv<<<dim3(C_CH / 128, HW / 256, BATCH), 512, 0, stream>>>(vT, att, outT);

    // 7) GEMM4: out[b,o,p] = w_out . outT^T + b_out + x  (M=768,N=1024,K=768),
    //    specialized 256x128, f32 out + residual
    gemm4_proj<<<dim3(HW / 128, C_CH / 256, BATCH), 512, 0, stream>>>(
        woutB, outT, b_out, x, (float*)d_out);
}